// Round 2
// baseline (1836.902 us; speedup 1.0000x reference)
//
#include <hip/hip_runtime.h>

#define LDIM 50
#define MBIN 262144
#define ODIM 155
#define VOCABSZ 100

// workspace layout (floats)
#define WS_T  0        // 6*100*50 = 30000 : T[s][v][d], s=0 pe-slot (b_pred folded), s=1..5 ve-slots
#define WS_TB 30000    // 100*50 : oe[v] @ W_bin[50:100] + b_bin
#define WS_LG 35000    // 300 : attention logits  [0..99]=pe, [100..199]=ve, [200..299]=oe

// ---------------------------------------------------------------------------
// Precompute vocab-indexed tables (trivial cost, ~2 MFLOP)
// ---------------------------------------------------------------------------
__global__ __launch_bounds__(64) void precompute_kernel(
    const float* __restrict__ pe, const float* __restrict__ ve, const float* __restrict__ oe,
    const float* __restrict__ W_pred, const float* __restrict__ b_pred,
    const float* __restrict__ W_bin, const float* __restrict__ b_bin,
    const float* __restrict__ W_att, const float* __restrict__ b_att,
    float* __restrict__ ws)
{
    const int bid = blockIdx.x;
    const int t = threadIdx.x;
    if (bid < 600) {
        const int s = bid / VOCABSZ, v = bid % VOCABSZ;
        if (t < LDIM) {
            const float* E = (s == 0) ? pe : ve;
            float acc = (s == 0) ? b_pred[t] : 0.0f;
            for (int e = 0; e < LDIM; ++e)
                acc += E[v*LDIM + e] * W_pred[(s*LDIM + e)*LDIM + t];
            ws[WS_T + (s*VOCABSZ + v)*LDIM + t] = acc;
        }
    } else if (bid < 700) {
        const int v = bid - 600;
        if (t < LDIM) {
            float acc = b_bin[t];
            for (int e = 0; e < LDIM; ++e)
                acc += oe[v*LDIM + e] * W_bin[(LDIM + e)*LDIM + t];
            ws[WS_TB + v*LDIM + t] = acc;
        }
    } else {
        const int g = (bid - 700)*64 + t;
        if (g < 300) {
            const int which = g / VOCABSZ, v = g % VOCABSZ;
            const float* E = (which == 0) ? pe : ((which == 1) ? ve : oe);
            float acc = b_att[0];
            for (int e = 0; e < LDIM; ++e)
                acc += E[v*LDIM + e] * W_att[e];
            ws[WS_LG + g] = acc;
        }
    }
}

// ---------------------------------------------------------------------------
// Build one predicate node's h_pred into hout[] (VGPR array, fully unrolled),
// return exp(h.W_att + b_att) — unnormalized stage-2 softmax weight.
// ---------------------------------------------------------------------------
__device__ __forceinline__ float build_pred_node(
    int n, const int* __restrict__ pred_ids, const int* __restrict__ var_ids,
    const float* __restrict__ pe, const float* __restrict__ ve,
    const float* __restrict__ T, const float* __restrict__ lg,
    const float* __restrict__ W_att, float batt, float* __restrict__ hout)
{
    const int p = pred_ids[n];
    int v[5];
#pragma unroll
    for (int s = 0; s < 5; ++s) v[s] = var_ids[n*5 + s];

    const float e0 = __expf(lg[p]);
    float ek[5];
    float den = e0;
#pragma unroll
    for (int s = 0; s < 5; ++s) { ek[s] = __expf(lg[VOCABSZ + v[s]]); den += ek[s]; }
    const float inv = 1.0f / den;

    float lin[LDIM], num[LDIM];
    {
        const float2* t0 = reinterpret_cast<const float2*>(T + p*LDIM);
        const float2* p0 = reinterpret_cast<const float2*>(pe + p*LDIM);
#pragma unroll
        for (int i = 0; i < LDIM/2; ++i) {
            float2 a = t0[i], b = p0[i];
            lin[2*i] = a.x;  lin[2*i+1] = a.y;
            num[2*i] = e0*b.x; num[2*i+1] = e0*b.y;
        }
    }
#pragma unroll
    for (int s = 0; s < 5; ++s) {
        const float2* tr = reinterpret_cast<const float2*>(T + ((s+1)*VOCABSZ + v[s])*LDIM);
        const float2* er = reinterpret_cast<const float2*>(ve + v[s]*LDIM);
        const float w = ek[s];
#pragma unroll
        for (int i = 0; i < LDIM/2; ++i) {
            float2 a = tr[i], b = er[i];
            lin[2*i]   += a.x; lin[2*i+1] += a.y;
            num[2*i]   += w*b.x; num[2*i+1] += w*b.y;
        }
    }

    float l = batt;
#pragma unroll
    for (int d = 0; d < LDIM; ++d) {
        float hv = fmaxf(lin[d], 0.0f) + num[d]*inv;
        hout[d] = hv;
        l += hv * W_att[d];
    }
    return __expf(l);
}

// ---------------------------------------------------------------------------
// Fused main kernel: one thread per binary node. All h vectors in VGPRs
// (every matvec fully unrolled -> compile-time indices, scalar weight loads).
// LDS used only for the coalesced store transpose (per-wave buffer, no sync).
// ---------------------------------------------------------------------------
__global__ __launch_bounds__(256, 3) void fused_kernel(
    const float* __restrict__ pe, const float* __restrict__ ve, const float* __restrict__ oe,
    const float* __restrict__ W_bin,
    const float* __restrict__ W_un, const float* __restrict__ b_un,
    const float* __restrict__ W_univ, const float* __restrict__ b_univ,
    const float* __restrict__ W_att, const float* __restrict__ b_att,
    const float* __restrict__ W_fin, const float* __restrict__ b_fin,
    const int* __restrict__ pred_ids, const int* __restrict__ var_ids,
    const int* __restrict__ op_ids,
    const float* __restrict__ ws, float* __restrict__ out)
{
    __shared__ float sb[4][64*33];   // per-wave store-transpose buffer

    const int j = blockIdx.x * 256 + threadIdx.x;
    const int wave = threadIdx.x >> 6;
    const int lane = threadIdx.x & 63;
    float* sw = sb[wave];

    const float* T  = ws + WS_T;
    const float* Tb = ws + WS_TB;
    const float* lg = ws + WS_LG;
    const float batt = b_att[0];

    // ---- predicate node B = 2j+1 (built first to cap register pressure) ----
    float hB[LDIM];
    const float w2 = build_pred_node(2*j+1, pred_ids, var_ids, pe, ve, T, lg, W_att, batt, hB);

    // ---- predicate node A = 2j ----
    float hA[LDIM];
    const float w0 = build_pred_node(2*j, pred_ids, var_ids, pe, ve, T, lg, W_att, batt, hA);

    const int op = op_ids[j];
    const float w1 = __expf(lg[2*VOCABSZ + op]);
    const float inv2 = 1.0f / (w0 + w1 + w2);

    // ---- lin2 = Tb[op] + hA @ W_bin[0:50] + hB @ W_bin[100:150] ----
    float lin2[LDIM];
    {
        const float2* r = reinterpret_cast<const float2*>(Tb + op*LDIM);
#pragma unroll
        for (int i = 0; i < LDIM/2; ++i) { float2 t2 = r[i]; lin2[2*i] = t2.x; lin2[2*i+1] = t2.y; }
    }
#pragma unroll
    for (int e = 0; e < LDIM; ++e) {
        const float he = hA[e];
        const float* wr = W_bin + e*LDIM;            // uniform -> s_load stream
#pragma unroll
        for (int d = 0; d < LDIM; ++d) lin2[d] += he * wr[d];
    }
#pragma unroll
    for (int e = 0; e < LDIM; ++e) {
        const float he = hB[e];
        const float* wr = W_bin + (2*LDIM + e)*LDIM;
#pragma unroll
        for (int d = 0; d < LDIM; ++d) lin2[d] += he * wr[d];
    }

    // ---- h_bin = relu(lin2) + inv2*(w0*hA + w2*hB + w1*oe[op]) ----
    float h[LDIM];
    {
        const float2* orow = reinterpret_cast<const float2*>(oe + op*LDIM);
#pragma unroll
        for (int i = 0; i < LDIM/2; ++i) {
            float2 t2 = orow[i];
            h[2*i]   = fmaxf(lin2[2*i],   0.0f) + (w0*hA[2*i]   + w2*hB[2*i]   + w1*t2.x)*inv2;
            h[2*i+1] = fmaxf(lin2[2*i+1], 0.0f) + (w0*hA[2*i+1] + w2*hB[2*i+1] + w1*t2.y)*inv2;
        }
    }

    // ---- h_un = relu(h @ W_un + b_un) ----
    {
        float acc[LDIM];
#pragma unroll
        for (int d = 0; d < LDIM; ++d) acc[d] = b_un[d];
#pragma unroll
        for (int e = 0; e < LDIM; ++e) {
            const float he = h[e];
            const float* wr = W_un + e*LDIM;
#pragma unroll
            for (int d = 0; d < LDIM; ++d) acc[d] += he * wr[d];
        }
#pragma unroll
        for (int d = 0; d < LDIM; ++d) h[d] = fmaxf(acc[d], 0.0f);
    }

    // ---- h_q = relu(h @ W_univ + b_univ) ----
    {
        float acc[LDIM];
#pragma unroll
        for (int d = 0; d < LDIM; ++d) acc[d] = b_univ[d];
#pragma unroll
        for (int e = 0; e < LDIM; ++e) {
            const float he = h[e];
            const float* wr = W_univ + e*LDIM;
#pragma unroll
            for (int d = 0; d < LDIM; ++d) acc[d] += he * wr[d];
        }
#pragma unroll
        for (int d = 0; d < LDIM; ++d) h[d] = fmaxf(acc[d], 0.0f);
    }

    // ---- out row = h @ W_fin + b_fin, 5 chunks of 31; LDS-transposed stores ----
    const int rowbase = blockIdx.x*256 + wave*64;     // first node of this wave
    for (int c = 0; c < 5; ++c) {
        float acc[31];
        const int obase = c * 31;
#pragma unroll
        for (int o = 0; o < 31; ++o) acc[o] = b_fin[obase + o];
#pragma unroll
        for (int d = 0; d < LDIM; ++d) {
            const float hq = h[d];
            const float* wr = W_fin + d*ODIM + obase;
#pragma unroll
            for (int o = 0; o < 31; ++o) acc[o] += hq * wr[o];
        }
        // stage: stride-33 rows -> conflict-free
#pragma unroll
        for (int o = 0; o < 31; ++o) sw[lane*33 + o] = acc[o];
        // wave-synchronous read-back + coalesced store (64x31 values, 31 iters)
        float* gb = out + (size_t)rowbase * ODIM + obase;
#pragma unroll
        for (int it = 0; it < 31; ++it) {
            const int f = it*64 + lane;
            const int row = f / 31;
            const int col = f - row*31;
            gb[row*ODIM + col] = sw[row*33 + col];
        }
    }
}

// ---------------------------------------------------------------------------
extern "C" void kernel_launch(void* const* d_in, const int* in_sizes, int n_in,
                              void* d_out, int out_size, void* d_ws, size_t ws_size,
                              hipStream_t stream) {
    const float* pe     = (const float*)d_in[0];
    const float* ve     = (const float*)d_in[1];
    const float* oe     = (const float*)d_in[2];
    const float* W_pred = (const float*)d_in[3];
    const float* b_pred = (const float*)d_in[4];
    const float* W_bin  = (const float*)d_in[5];
    const float* b_bin  = (const float*)d_in[6];
    const float* W_un   = (const float*)d_in[7];
    const float* b_un   = (const float*)d_in[8];
    const float* W_univ = (const float*)d_in[9];
    const float* b_univ = (const float*)d_in[10];
    const float* W_att  = (const float*)d_in[11];
    const float* b_att  = (const float*)d_in[12];
    const float* W_fin  = (const float*)d_in[13];
    const float* b_fin  = (const float*)d_in[14];
    const int* pred_ids = (const int*)d_in[15];
    const int* var_ids  = (const int*)d_in[16];
    const int* op_ids   = (const int*)d_in[17];
    float* out = (float*)d_out;
    float* ws  = (float*)d_ws;

    precompute_kernel<<<705, 64, 0, stream>>>(pe, ve, oe, W_pred, b_pred,
                                              W_bin, b_bin, W_att, b_att, ws);
    fused_kernel<<<MBIN/256, 256, 0, stream>>>(pe, ve, oe, W_bin, W_un, b_un,
                                               W_univ, b_univ, W_att, b_att,
                                               W_fin, b_fin, pred_ids, var_ids,
                                               op_ids, ws, out);
}

// Round 3
// 695.384 us; speedup vs baseline: 2.6416x; 2.6416x over previous
//
#include <hip/hip_runtime.h>

#define LDIM 50
#define MBIN 262144
#define ODIM 155
#define VOCABSZ 100

// workspace layout (floats) — produced by precompute_kernel
#define WS_T  0        // 6*100*50 = 30000 : T[s][v][d], s=0 pe-slot (b_pred folded), s=1..5 ve-slots
#define WS_TB 30000    // 100*50 : oe[v] @ W_bin[50:100] + b_bin
#define WS_LG 35000    // 300 : attention logits  [0..99]=pe, [100..199]=ve, [200..299]=oe

// dynamic-LDS layout (floats) for fused kernel
#define O_T   0        // 30000 : T tables              (phase3: reused for store-transpose)
#define O_PE  30000    // 5000  : pe                    (phase2: reused for Tb)
#define O_VE  35000    // 5000  : ve                    (phase2: reused for oe)
#define O_LG  40000    // 304   : attention logits
#define LDS_FLOATS 40304

// ---------------------------------------------------------------------------
// Precompute vocab-indexed tables (trivial cost, ~2 MFLOP)
// ---------------------------------------------------------------------------
__global__ __launch_bounds__(64) void precompute_kernel(
    const float* __restrict__ pe, const float* __restrict__ ve, const float* __restrict__ oe,
    const float* __restrict__ W_pred, const float* __restrict__ b_pred,
    const float* __restrict__ W_bin, const float* __restrict__ b_bin,
    const float* __restrict__ W_att, const float* __restrict__ b_att,
    float* __restrict__ ws)
{
    const int bid = blockIdx.x;
    const int t = threadIdx.x;
    if (bid < 600) {
        const int s = bid / VOCABSZ, v = bid % VOCABSZ;
        if (t < LDIM) {
            const float* E = (s == 0) ? pe : ve;
            float acc = (s == 0) ? b_pred[t] : 0.0f;
            for (int e = 0; e < LDIM; ++e)
                acc += E[v*LDIM + e] * W_pred[(s*LDIM + e)*LDIM + t];
            ws[WS_T + (s*VOCABSZ + v)*LDIM + t] = acc;
        }
    } else if (bid < 700) {
        const int v = bid - 600;
        if (t < LDIM) {
            float acc = b_bin[t];
            for (int e = 0; e < LDIM; ++e)
                acc += oe[v*LDIM + e] * W_bin[(LDIM + e)*LDIM + t];
            ws[WS_TB + v*LDIM + t] = acc;
        }
    } else {
        const int g = (bid - 700)*64 + t;
        if (g < 300) {
            const int which = g / VOCABSZ, v = g % VOCABSZ;
            const float* E = (which == 0) ? pe : ((which == 1) ? ve : oe);
            float acc = b_att[0];
            for (int e = 0; e < LDIM; ++e)
                acc += E[v*LDIM + e] * W_att[e];
            ws[WS_LG + g] = acc;
        }
    }
}

// ---------------------------------------------------------------------------
// Build h_pred for node with ids (p, v[5]) from LDS tables.
// Chunk-outer / row-inner: only hout[] stays live (50 regs).
// Returns exp(h.W_att + b_att).
// ---------------------------------------------------------------------------
__device__ __forceinline__ float build_pred_node_lds(
    int p, const int* v, const float* __restrict__ lds,
    const float* __restrict__ W_att, float batt, float* __restrict__ hout)
{
    const float* lg = lds + O_LG;
    const float e0 = __expf(lg[p]);
    float ek[5];
    float den = e0;
#pragma unroll
    for (int s = 0; s < 5; ++s) { ek[s] = __expf(lg[VOCABSZ + v[s]]); den += ek[s]; }
    const float inv = 1.0f / den;

    const float2* T2  = reinterpret_cast<const float2*>(lds + O_T);
    const float2* pe2 = reinterpret_cast<const float2*>(lds + O_PE);
    const float2* ve2 = reinterpret_cast<const float2*>(lds + O_VE);
    const int rT0 = p*(LDIM/2);
    int rTs[5], rVs[5];
#pragma unroll
    for (int s = 0; s < 5; ++s) {
        rTs[s] = ((s+1)*VOCABSZ + v[s])*(LDIM/2);
        rVs[s] = v[s]*(LDIM/2);
    }

    float l = batt;
#pragma unroll
    for (int i = 0; i < LDIM/2; ++i) {
        float2 lin = T2[rT0 + i];
        float2 pv  = pe2[rT0 + i];
        float nx = e0*pv.x, ny = e0*pv.y;
#pragma unroll
        for (int s = 0; s < 5; ++s) {
            float2 a = T2[rTs[s] + i];
            float2 b = ve2[rVs[s] + i];
            lin.x += a.x; lin.y += a.y;
            nx += ek[s]*b.x; ny += ek[s]*b.y;
        }
        float hx = fmaxf(lin.x, 0.0f) + nx*inv;
        float hy = fmaxf(lin.y, 0.0f) + ny*inv;
        hout[2*i] = hx; hout[2*i+1] = hy;
        l += hx*W_att[2*i] + hy*W_att[2*i+1];
    }
    return __expf(l);
}

// ---------------------------------------------------------------------------
// Fused kernel: one thread per binary node (builds BOTH its pred nodes).
// LDS lifecycle: [T|pe|ve|lg] -> phase2 overwrites pe/ve with [Tb|oe] ->
// phase3 reuses T region for per-wave store transpose.
// ---------------------------------------------------------------------------
__global__ __launch_bounds__(512, 2) void fused_kernel(
    const float* __restrict__ pe, const float* __restrict__ ve, const float* __restrict__ oe,
    const float* __restrict__ W_bin,
    const float* __restrict__ W_un, const float* __restrict__ b_un,
    const float* __restrict__ W_univ, const float* __restrict__ b_univ,
    const float* __restrict__ W_att, const float* __restrict__ b_att,
    const float* __restrict__ W_fin, const float* __restrict__ b_fin,
    const int* __restrict__ pred_ids, const int* __restrict__ var_ids,
    const int* __restrict__ op_ids,
    const float* __restrict__ ws, float* __restrict__ out)
{
    extern __shared__ float lds[];
    const int tid = threadIdx.x;
    const int j = blockIdx.x * 512 + tid;

    // ---- stage T + pe + ve + lg into LDS (coalesced float4) ----
    {
        const float4* src = reinterpret_cast<const float4*>(ws + WS_T);     // 7500 vec4
        float4* dst = reinterpret_cast<float4*>(lds + O_T);
        for (int i = tid; i < 7500; i += 512) dst[i] = src[i];
        const float4* s2 = reinterpret_cast<const float4*>(pe);             // 1250
        float4* d2 = reinterpret_cast<float4*>(lds + O_PE);
        for (int i = tid; i < 1250; i += 512) d2[i] = s2[i];
        const float4* s3 = reinterpret_cast<const float4*>(ve);
        float4* d3 = reinterpret_cast<float4*>(lds + O_VE);
        for (int i = tid; i < 1250; i += 512) d3[i] = s3[i];
        if (tid < 300) lds[O_LG + tid] = ws[WS_LG + tid];
    }
    __syncthreads();

    const float batt = b_att[0];

    // ---- phase 1: build both predicate nodes ----
    int vA[5], vB[5];
    const int pA = pred_ids[2*j], pB = pred_ids[2*j+1];
#pragma unroll
    for (int s = 0; s < 5; ++s) { vA[s] = var_ids[(2*j)*5 + s]; vB[s] = var_ids[(2*j+1)*5 + s]; }

    float hA[LDIM], hB[LDIM];
    const float w0 = build_pred_node_lds(pA, vA, lds, W_att, batt, hA);
    const float w2 = build_pred_node_lds(pB, vB, lds, W_att, batt, hB);

    const int op = op_ids[j];
    const float w1 = __expf(lds[O_LG + 2*VOCABSZ + op]);
    const float inv2 = 1.0f / (w0 + w1 + w2);

    __syncthreads();   // all phase-1 LDS reads done

    // ---- stage Tb + oe into the (dead) pe/ve region ----
    {
        const float4* src = reinterpret_cast<const float4*>(ws + WS_TB);    // 1250 vec4
        float4* dst = reinterpret_cast<float4*>(lds + O_PE);
        for (int i = tid; i < 1250; i += 512) dst[i] = src[i];
        const float4* s2 = reinterpret_cast<const float4*>(oe);
        float4* d2 = reinterpret_cast<float4*>(lds + O_VE);
        for (int i = tid; i < 1250; i += 512) d2[i] = s2[i];
    }
    __syncthreads();

    // ---- phase 2: lin2 = Tb[op] + hA @ Wbin[0:50] + hB @ Wbin[100:150] ----
    float lin2[LDIM];
    {
        const float2* Tb2 = reinterpret_cast<const float2*>(lds + O_PE);
        const int r = op*(LDIM/2);
#pragma unroll
        for (int i = 0; i < LDIM/2; ++i) { float2 t2 = Tb2[r+i]; lin2[2*i] = t2.x; lin2[2*i+1] = t2.y; }
    }
#pragma unroll
    for (int e = 0; e < LDIM; ++e) {
        const float a = hA[e], b = hB[e];
        const float* wa = W_bin + e*LDIM;              // uniform -> s_load stream
        const float* wb = W_bin + (2*LDIM + e)*LDIM;
#pragma unroll
        for (int d = 0; d < LDIM; ++d) lin2[d] += a*wa[d] + b*wb[d];
    }

    // ---- h_bin = relu(lin2) + inv2*(w0*hA + w2*hB + w1*oe[op]) ----
    float h[LDIM];
    {
        const float2* oe2 = reinterpret_cast<const float2*>(lds + O_VE);
        const int r = op*(LDIM/2);
#pragma unroll
        for (int i = 0; i < LDIM/2; ++i) {
            float2 t2 = oe2[r+i];
            h[2*i]   = fmaxf(lin2[2*i],   0.0f) + (w0*hA[2*i]   + w2*hB[2*i]   + w1*t2.x)*inv2;
            h[2*i+1] = fmaxf(lin2[2*i+1], 0.0f) + (w0*hA[2*i+1] + w2*hB[2*i+1] + w1*t2.y)*inv2;
        }
    }

    // ---- h_un = relu(h @ W_un + b_un); h_q = relu(h_un @ W_univ + b_univ) ----
    {
        float acc[LDIM];
#pragma unroll
        for (int d = 0; d < LDIM; ++d) acc[d] = b_un[d];
#pragma unroll
        for (int e = 0; e < LDIM; ++e) {
            const float he = h[e];
            const float* wr = W_un + e*LDIM;
#pragma unroll
            for (int d = 0; d < LDIM; ++d) acc[d] += he * wr[d];
        }
#pragma unroll
        for (int d = 0; d < LDIM; ++d) h[d] = fmaxf(acc[d], 0.0f);
    }
    {
        float acc[LDIM];
#pragma unroll
        for (int d = 0; d < LDIM; ++d) acc[d] = b_univ[d];
#pragma unroll
        for (int e = 0; e < LDIM; ++e) {
            const float he = h[e];
            const float* wr = W_univ + e*LDIM;
#pragma unroll
            for (int d = 0; d < LDIM; ++d) acc[d] += he * wr[d];
        }
#pragma unroll
        for (int d = 0; d < LDIM; ++d) h[d] = fmaxf(acc[d], 0.0f);
    }

    // ---- phase 3: out row = h @ W_fin + b_fin, LDS-transposed coalesced stores
    //      (per-wave buffer in the dead T region; wave-synchronous, no barrier)
    const int wave = tid >> 6, lane = tid & 63;
    float* sw = lds + O_T + wave * (64*33);
    const int rowbase = blockIdx.x*512 + wave*64;
    for (int c = 0; c < 5; ++c) {
        float acc[31];
        const int obase = c * 31;
#pragma unroll
        for (int o = 0; o < 31; ++o) acc[o] = b_fin[obase + o];
#pragma unroll
        for (int d = 0; d < LDIM; ++d) {
            const float hq = h[d];
            const float* wr = W_fin + d*ODIM + obase;
#pragma unroll
            for (int o = 0; o < 31; ++o) acc[o] += hq * wr[o];
        }
#pragma unroll
        for (int o = 0; o < 31; ++o) sw[lane*33 + o] = acc[o];
        float* gb = out + (size_t)rowbase * ODIM + obase;
#pragma unroll
        for (int it = 0; it < 31; ++it) {
            const int f = it*64 + lane;
            const int row = f / 31;
            const int col = f - row*31;
            gb[row*ODIM + col] = sw[row*33 + col];
        }
    }
}

// ---------------------------------------------------------------------------
extern "C" void kernel_launch(void* const* d_in, const int* in_sizes, int n_in,
                              void* d_out, int out_size, void* d_ws, size_t ws_size,
                              hipStream_t stream) {
    const float* pe     = (const float*)d_in[0];
    const float* ve     = (const float*)d_in[1];
    const float* oe     = (const float*)d_in[2];
    const float* W_pred = (const float*)d_in[3];
    const float* b_pred = (const float*)d_in[4];
    const float* W_bin  = (const float*)d_in[5];
    const float* b_bin  = (const float*)d_in[6];
    const float* W_un   = (const float*)d_in[7];
    const float* b_un   = (const float*)d_in[8];
    const float* W_univ = (const float*)d_in[9];
    const float* b_univ = (const float*)d_in[10];
    const float* W_att  = (const float*)d_in[11];
    const float* b_att  = (const float*)d_in[12];
    const float* W_fin  = (const float*)d_in[13];
    const float* b_fin  = (const float*)d_in[14];
    const int* pred_ids = (const int*)d_in[15];
    const int* var_ids  = (const int*)d_in[16];
    const int* op_ids   = (const int*)d_in[17];
    float* out = (float*)d_out;
    float* ws  = (float*)d_ws;

    const int lds_bytes = LDS_FLOATS * 4;   // 161216 B
    (void)hipFuncSetAttribute((const void*)fused_kernel,
                              hipFuncAttributeMaxDynamicSharedMemorySize, lds_bytes);

    precompute_kernel<<<705, 64, 0, stream>>>(pe, ve, oe, W_pred, b_pred,
                                              W_bin, b_bin, W_att, b_att, ws);
    fused_kernel<<<MBIN/512, 512, lds_bytes, stream>>>(pe, ve, oe, W_bin, W_un, b_un,
                                                       W_univ, b_univ, W_att, b_att,
                                                       W_fin, b_fin, pred_ids, var_ids,
                                                       op_ids, ws, out);
}